// Round 3
// baseline (224.524 us; speedup 1.0000x reference)
//
#include <hip/hip_runtime.h>

#define D   256
#define BM  64      // rows per block
#define BN  128     // codes per group
#define NSTAGES 128 // 16 groups x 8 half-chunk stages (K=32 each)

typedef __attribute__((ext_vector_type(8))) short v8s;   // 8 bf16 = 4 VGPR
typedef __attribute__((ext_vector_type(4))) float v4f;
#define MFMA16 __builtin_amdgcn_mfma_f32_16x16x32_bf16

// counted vmcnt wait; "memory" clobber pins VMEM issue order around it.
#define WAITVM(N) asm volatile("s_waitcnt vmcnt(" #N ")" ::: "memory")

static __device__ inline unsigned short f2bf(float f) {          // RNE
    unsigned u = __float_as_uint(f);
    return (unsigned short)((u + 0x7fffu + ((u >> 16) & 1u)) >> 16);
}
static __device__ inline float bf2f(unsigned short s) {
    return __uint_as_float(((unsigned)s) << 16);
}

// async global->LDS, 16 B per lane. LDS dest must be wave-uniform (HW adds lane*16).
static __device__ inline void gl_lds16(const unsigned short* g, unsigned short* l) {
    __builtin_amdgcn_global_load_lds(
        (const __attribute__((address_space(1))) unsigned int*)g,
        (__attribute__((address_space(3))) unsigned int*)l, 16, 0, 0);
}

// ---------------- kernel 1a: exact c2 (+ zero the loss accumulator) ----------------
__global__ void vq_prep_c2(const float* __restrict__ cb, float* __restrict__ c2,
                           float* __restrict__ loss) {
    const int row  = blockIdx.x;
    const int lane = threadIdx.x;  // 64
    if (row == 0 && lane == 0) loss[0] = 0.0f;
    const float4 v = *reinterpret_cast<const float4*>(cb + (size_t)row * D + lane * 4);
    float s = v.x * v.x + v.y * v.y + v.z * v.z + v.w * v.w;
    #pragma unroll
    for (int off = 32; off > 0; off >>= 1) s += __shfl_down(s, off, 64);
    if (lane == 0) c2[row] = s;
}

// ---------------- kernel 1b: codebook -> bf16 hi/lo, chunk-major pre-swizzled ----------------
// Chunk (nc_i, kc_i) = 128 codes x 64 k = 1024 granules of 16 B (8 bf16).
// Granule p within chunk: seg = p>>7 (k-octet 0..7), n = (p&127) ^ seg.
// Half-chunks (seg 0..3 / 4..7) are contiguous 8 KB runs -> DMA'd as stages.
// 256 blocks (4 per chunk) for full-CU occupancy.
__global__ void vq_prep_sw(const float* __restrict__ cb,
                           unsigned short* __restrict__ cbh, unsigned short* __restrict__ cbl) {
    const int b     = blockIdx.x;          // 256 blocks
    const int chunk = b >> 2;
    const int nc = (chunk >> 2) * BN;
    const int kc = (chunk & 3) * 64;
    const int p   = (b & 3) * 256 + threadIdx.x;
    const int seg = p >> 7;
    const int n   = (p & 127) ^ seg;
    const float* src = cb + (size_t)(nc + n) * D + kc + seg * 8;
    const float4 f0 = *reinterpret_cast<const float4*>(src);
    const float4 f1 = *reinterpret_cast<const float4*>(src + 4);
    const float f[8] = {f0.x, f0.y, f0.z, f0.w, f1.x, f1.y, f1.z, f1.w};
    v8s h, l;
    #pragma unroll
    for (int j = 0; j < 8; ++j) {
        unsigned short hb = f2bf(f[j]);
        h[j] = (short)hb;
        l[j] = (short)f2bf(f[j] - bf2f(hb));
    }
    const size_t o = ((size_t)chunk * 1024 + p) * 8;
    *reinterpret_cast<v8s*>(cbh + o) = h;
    *reinterpret_cast<v8s*>(cbl + o) = l;
}

// ---------------- kernel 2: MFMA argmin + fused gather/loss ----------------
// Stage s = half-chunk (128 codes x 32 k) = 8 KB h + 8 KB l in ring slot s&3.
// Per stage: WAITVM(4) [own s loads landed; s+1 in flight] -> s_barrier [all
// waves' s loads certified in LDS; all waves done with slot (s+2)&3's old data]
// -> issue s+2 (4 DMAs) -> 8 ds_read_b128 + 24 MFMA16 (setprio-wrapped).
// Prefetch depth 2: the wait targets loads issued two compute regions ago.
// vmcnt never drains in the main loop (tail peeled).
__global__ __launch_bounds__(256, 2) void vq_argmin_mfma(
        const float* __restrict__ x, const float* __restrict__ cb,
        const unsigned short* __restrict__ cbh, const unsigned short* __restrict__ cbl,
        const float* __restrict__ c2, float* __restrict__ idx_out,
        float* __restrict__ qout, float* __restrict__ loss, float scale, int N) {
    __shared__ unsigned short ring[4][8192];   // 4 x (8 KB h | 8 KB l) = 64 KB
    __shared__ float c2s[2048];                // 8 KB  -> 72 KB total, 2 blocks/CU

    const int tid  = threadIdx.x;
    const int w    = tid >> 6;
    const int lane = tid & 63;
    const int col  = lane & 15;     // MFMA col / A-row selector
    const int quad = lane >> 4;     // k-octet selector within the 32-k stage
    const int mg   = w >> 1;
    const int ng   = w & 1;
    const int m0   = blockIdx.x * BM;

    // per-wave staging pointers: wave w stages granules [w*128, w*128+128) of each stage
    const unsigned short* gh0 = cbh + ((size_t)(w * 128 + lane)) * 8;
    const unsigned short* gl0 = cbl + ((size_t)(w * 128 + lane)) * 8;

    // prologue: issue stages 0 and 1 (slots 0,1); they fly during setup below
    {
        unsigned short* d0 = &ring[0][0] + w * 1024;
        unsigned short* d1 = &ring[1][0] + w * 1024;
        gl_lds16(gh0,              d0);
        gl_lds16(gh0 + 512,        d0 + 512);
        gl_lds16(gl0,              d0 + 4096);
        gl_lds16(gl0 + 512,        d0 + 4096 + 512);
        gl_lds16(gh0 + 4096,       d1);
        gl_lds16(gh0 + 4096 + 512, d1 + 512);
        gl_lds16(gl0 + 4096,       d1 + 4096);
        gl_lds16(gl0 + 4096 + 512, d1 + 4096 + 512);
    }

    // ---- c2 -> LDS ----
    {
        const int o = tid * 8;
        if (o < N) {
            const float4 a = *reinterpret_cast<const float4*>(c2 + o);
            const float4 b = *reinterpret_cast<const float4*>(c2 + o + 4);
            *reinterpret_cast<float4*>(&c2s[o])     = a;
            *reinterpret_cast<float4*>(&c2s[o + 4]) = b;
        }
    }

    // ---- A-frags: rows m0 + mg*32 + mt*16 + col, full K, hi+lo (128 VGPR) ----
    v8s xh[2][8], xl[2][8];
    #pragma unroll
    for (int mt = 0; mt < 2; ++mt) {
        const float* xr = x + (size_t)(m0 + mg * 32 + mt * 16 + col) * D;
        #pragma unroll
        for (int ks = 0; ks < 8; ++ks) {
            const int kb = ks * 32 + quad * 8;
            const float4 f0 = *reinterpret_cast<const float4*>(xr + kb);
            const float4 f1 = *reinterpret_cast<const float4*>(xr + kb + 4);
            float f[8] = {f0.x, f0.y, f0.z, f0.w, f1.x, f1.y, f1.z, f1.w};
            v8s h, l;
            #pragma unroll
            for (int j = 0; j < 8; ++j) {
                unsigned short hb = f2bf(f[j]);
                h[j] = (short)hb;
                l[j] = (short)f2bf(f[j] - bf2f(hb));
            }
            xh[mt][ks] = h; xl[mt][ks] = l;
        }
    }

    // ---- precomputed swizzled LDS byte offsets ----
    // stage-local read: code n = ng*64+nt*16+col at local octet quad; global
    // seg = hs*4+quad -> granule quad*128 + (n ^ (hs*4+quad)).
    // hs=1 differs from hs=0 by XOR 4 on the granule index = XOR 64 on bytes.
    unsigned offA[4], offB[4];
    #pragma unroll
    for (int nt = 0; nt < 4; ++nt) {
        const int n = ng * 64 + nt * 16 + col;
        offA[nt] = (unsigned)((quad * 128 + (n ^ quad)) * 16);
        offB[nt] = offA[nt] ^ 64;
    }

    float runmin[2][4];
    int   runidx[2][4];
    #pragma unroll
    for (int mt = 0; mt < 2; ++mt)
        #pragma unroll
        for (int r = 0; r < 4; ++r) { runmin[mt][r] = 3.4e38f; runidx[mt][r] = 0; }

    v4f acc[4][2];
    #pragma unroll
    for (int nt = 0; nt < 4; ++nt)
        #pragma unroll
        for (int mt = 0; mt < 2; ++mt) acc[nt][mt] = 0.0f;

    __syncthreads();   // publish c2s; full drain (prologue-once) -> stage 0/1 landed

#define STAGE(U, KS0, ISSUE, WVM)                                              \
    {                                                                          \
        WAITVM(WVM);                                                           \
        __builtin_amdgcn_s_barrier();                                          \
        if (!(ISSUE)) __builtin_amdgcn_sched_barrier(0);                       \
        if (ISSUE) {                                                           \
            const int s2 = stage_base + (U) + 2;                               \
            const unsigned short* gh = gh0 + (size_t)s2 * 4096;                \
            const unsigned short* gl = gl0 + (size_t)s2 * 4096;                \
            unsigned short* dst = &ring[((U) + 2) & 3][0] + w * 1024;          \
            gl_lds16(gh,       dst);                                           \
            gl_lds16(gh + 512, dst + 512);                                     \
            gl_lds16(gl,       dst + 4096);                                    \
            gl_lds16(gl + 512, dst + 4096 + 512);                              \
        }                                                                      \
        __builtin_amdgcn_s_setprio(1);                                         \
        {                                                                      \
            const char* cbase = (const char*)&ring[(U) & 3][0];                \
            _Pragma("unroll")                                                  \
            for (int nt = 0; nt < 4; ++nt) {                                   \
                const unsigned off = ((U) & 1) ? offB[nt] : offA[nt];          \
                const v8s ch = *reinterpret_cast<const v8s*>(cbase + off);     \
                const v8s cl = *reinterpret_cast<const v8s*>(cbase + 8192 + off); \
                acc[nt][0] = MFMA16(xh[0][(KS0) + (U)], ch, acc[nt][0], 0, 0, 0); \
                acc[nt][1] = MFMA16(xh[1][(KS0) + (U)], ch, acc[nt][1], 0, 0, 0); \
                acc[nt][0] = MFMA16(xl[0][(KS0) + (U)], ch, acc[nt][0], 0, 0, 0); \
                acc[nt][1] = MFMA16(xl[1][(KS0) + (U)], ch, acc[nt][1], 0, 0, 0); \
                acc[nt][0] = MFMA16(xh[0][(KS0) + (U)], cl, acc[nt][0], 0, 0, 0); \
                acc[nt][1] = MFMA16(xh[1][(KS0) + (U)], cl, acc[nt][1], 0, 0, 0); \
            }                                                                  \
        }                                                                      \
        __builtin_amdgcn_s_setprio(0);                                         \
    }

#define FINALIZE(G)                                                            \
    {                                                                          \
        const int g_ = (G);                                                    \
        _Pragma("unroll")                                                      \
        for (int nt = 0; nt < 4; ++nt) {                                       \
            const int n = g_ * 128 + ng * 64 + nt * 16 + col;                  \
            const float c2n = c2s[n];                                          \
            _Pragma("unroll")                                                  \
            for (int mt = 0; mt < 2; ++mt) {                                   \
                _Pragma("unroll")                                              \
                for (int r = 0; r < 4; ++r) {                                  \
                    const float sv = c2n - 2.0f * acc[nt][mt][r];              \
                    if (sv < runmin[mt][r]) { runmin[mt][r] = sv; runidx[mt][r] = n; } \
                }                                                              \
                acc[nt][mt] = 0.0f;                                            \
            }                                                                  \
        }                                                                      \
    }

    for (int sb = 0; sb < 31; ++sb) {
        const int stage_base = sb * 4;
        if ((sb & 1) == 0) {
            STAGE(0, 0, 1, 4) STAGE(1, 0, 1, 4) STAGE(2, 0, 1, 4) STAGE(3, 0, 1, 4)
        } else {
            STAGE(0, 4, 1, 4) STAGE(1, 4, 1, 4) STAGE(2, 4, 1, 4) STAGE(3, 4, 1, 4)
            FINALIZE(sb >> 1)
        }
    }
    {   // peeled tail: stages 124..127 (sb = 31, odd -> KS0 = 4)
        const int stage_base = 124;
        STAGE(0, 4, 1, 4)   // 124: issue 126, wait 124
        STAGE(1, 4, 1, 4)   // 125: issue 127, wait 125
        STAGE(2, 4, 0, 4)   // 126: no issue; 8 in flight -> wait leaves 127's 4
        STAGE(3, 4, 0, 0)   // 127: drain
        FINALIZE(15)
    }
#undef STAGE
#undef FINALIZE

    // ---- merge: row = mg*32 + mt*16 + quad*4 + r ; slot = (ng*16 + col) ^ (row&31) ----
    __syncthreads();
    float* red_v = reinterpret_cast<float*>(&ring[0][0]);   // [64][32] f32, 8 KB
    int*   red_i = reinterpret_cast<int*>(&ring[1][0]);     // [64][32] i32, 8 KB
    #pragma unroll
    for (int mt = 0; mt < 2; ++mt)
        #pragma unroll
        for (int r = 0; r < 4; ++r) {
            const int row  = mg * 32 + mt * 16 + quad * 4 + r;
            const int slot = (ng * 16 + col) ^ (row & 31);
            red_v[row * 32 + slot] = runmin[mt][r];
            red_i[row * 32 + slot] = runidx[mt][r];
        }
    __syncthreads();
    float best = 3.4e38f;
    int   bidx = 0;
    if (tid < 64) {
        #pragma unroll 4
        for (int t = 0; t < 32; ++t) {
            const int  sl = t ^ (tid & 31);
            const float v = red_v[tid * 32 + sl];
            const int  id = red_i[tid * 32 + sl];
            if (v < best || (v == best && id < bidx)) { best = v; bidx = id; }
        }
        idx_out[m0 + tid] = (float)bidx;
    }
    __syncthreads();
    int* idx_sh = reinterpret_cast<int*>(&ring[2][0]);
    if (tid < 64) idx_sh[tid] = bidx;
    __syncthreads();

    // ---- fused gather + loss over this block's 64 rows (x tile is L2-hot) ----
    const float* xg2 = x + (size_t)m0 * D;
    float s = 0.0f;
    #pragma unroll
    for (int i = 0; i < 16; ++i) {
        const int gix = i * 256 + tid;      // float4-granule, 4096 total
        const int row = gix >> 6;
        const int k4  = (gix & 63) * 4;
        const int idx = idx_sh[row];
        const float4 c  = *reinterpret_cast<const float4*>(cb  + (size_t)idx * D + k4);
        const float4 xv = *reinterpret_cast<const float4*>(xg2 + (size_t)row * D + k4);
        *reinterpret_cast<float4*>(qout + (size_t)(m0 + row) * D + k4) = c;
        const float dx = c.x - xv.x, dy = c.y - xv.y, dz = c.z - xv.z, dw = c.w - xv.w;
        s += dx * dx + dy * dy + dz * dz + dw * dw;
    }
    #pragma unroll
    for (int off = 32; off > 0; off >>= 1) s += __shfl_down(s, off, 64);
    float* wsum = reinterpret_cast<float*>(&ring[3][0]);
    if ((tid & 63) == 0) wsum[tid >> 6] = s;
    __syncthreads();
    if (tid == 0) atomicAdd(loss, (wsum[0] + wsum[1] + wsum[2] + wsum[3]) * scale);
}

extern "C" void kernel_launch(void* const* d_in, const int* in_sizes, int n_in,
                              void* d_out, int out_size, void* d_ws, size_t ws_size,
                              hipStream_t stream) {
    const float* x  = (const float*)d_in[0];
    const float* cb = (const float*)d_in[1];
    const int M = in_sizes[0] / D;   // 32768
    const int N = in_sizes[1] / D;   // 2048

    float* qout    = (float*)d_out;
    float* idx_out = qout + (size_t)M * D;
    float* loss    = idx_out + M;

    // ws layout (bytes): c2 [0,8K) | cbh_sw [8K, +1M) | cbl_sw [+1M)
    char* wsb = (char*)d_ws;
    float*          c2  = (float*)wsb;
    unsigned short* cbh = (unsigned short*)(wsb + 8192);
    unsigned short* cbl = cbh + (size_t)N * D;

    vq_prep_c2<<<N, 64, 0, stream>>>(cb, c2, loss);
    vq_prep_sw<<<(N / BN) * 4 * 4, 256, 0, stream>>>(cb, cbh, cbl);
    const float scale = 2.0f / (float)((size_t)M * D);
    vq_argmin_mfma<<<M / BM, 256, 0, stream>>>(x, cb, cbh, cbl, c2, idx_out, qout,
                                               loss, scale, N);
}

// Round 6
// 223.683 us; speedup vs baseline: 1.0038x; 1.0038x over previous
//
#include <hip/hip_runtime.h>

#define D   256
#define BM  128     // rows per block (8 waves, 512 threads, 1 block stages per CU)
#define BN  128     // codes per group

typedef __attribute__((ext_vector_type(8))) short v8s;   // 8 bf16 = 4 VGPR
typedef __attribute__((ext_vector_type(4))) float v4f;
#define MFMA16 __builtin_amdgcn_mfma_f32_16x16x32_bf16

// counted vmcnt wait; "memory" clobber pins VMEM issue order around it.
#define WAITVM(N) asm volatile("s_waitcnt vmcnt(" #N ")" ::: "memory")
// compile-time scheduler fence: nothing may cross (runtime-free). Raw s_barrier
// is NOT a compiler memory fence — without this, LLVM may hoist a ds_read of
// the freshly-staged buffer above the barrier, reading another wave's staging
// region before that wave's WAITVM certified its DMA landed (the r5 race).
#define SCHEDFENCE() __builtin_amdgcn_sched_barrier(0)

static __device__ inline unsigned short f2bf(float f) {          // RNE
    unsigned u = __float_as_uint(f);
    return (unsigned short)((u + 0x7fffu + ((u >> 16) & 1u)) >> 16);
}
static __device__ inline float bf2f(unsigned short s) {
    return __uint_as_float(((unsigned)s) << 16);
}

// async global->LDS, 16 B per lane. LDS dest must be wave-uniform (HW adds lane*16).
static __device__ inline void gl_lds16(const unsigned short* g, unsigned short* l) {
    __builtin_amdgcn_global_load_lds(
        (const __attribute__((address_space(1))) unsigned int*)g,
        (__attribute__((address_space(3))) unsigned int*)l, 16, 0, 0);
}

// ---------------- kernel 1a: exact c2 (+ zero the loss accumulator) ----------------
__global__ void vq_prep_c2(const float* __restrict__ cb, float* __restrict__ c2,
                           float* __restrict__ loss) {
    const int row  = blockIdx.x;
    const int lane = threadIdx.x;  // 64
    if (row == 0 && lane == 0) loss[0] = 0.0f;
    const float4 v = *reinterpret_cast<const float4*>(cb + (size_t)row * D + lane * 4);
    float s = v.x * v.x + v.y * v.y + v.z * v.z + v.w * v.w;
    #pragma unroll
    for (int off = 32; off > 0; off >>= 1) s += __shfl_down(s, off, 64);
    if (lane == 0) c2[row] = s;
}

// ---------------- kernel 1b: codebook -> bf16 hi/lo, chunk-major pre-swizzled ----------------
// Chunk (nc_i, kc_i) = 128 codes x 64 k = 1024 granules of 16 B (8 bf16).
// Granule p within chunk: seg = p>>7 (k-octet 0..7), n = (p&127) ^ seg.
// Lane-linear DMA reproduces this in LDS: MFMA read octets (col 0..7, seg const)
// hit bank-groups (col^seg)&7, all distinct -> conflict-free.
__global__ void vq_prep_sw(const float* __restrict__ cb,
                           unsigned short* __restrict__ cbh, unsigned short* __restrict__ cbl) {
    const int b     = blockIdx.x;          // 256 blocks, 4 per chunk
    const int chunk = b >> 2;
    const int nc = (chunk >> 2) * BN;
    const int kc = (chunk & 3) * 64;
    const int p   = (b & 3) * 256 + threadIdx.x;
    const int seg = p >> 7;
    const int n   = (p & 127) ^ seg;
    const float* src = cb + (size_t)(nc + n) * D + kc + seg * 8;
    const float4 f0 = *reinterpret_cast<const float4*>(src);
    const float4 f1 = *reinterpret_cast<const float4*>(src + 4);
    const float f[8] = {f0.x, f0.y, f0.z, f0.w, f1.x, f1.y, f1.z, f1.w};
    v8s h, l;
    #pragma unroll
    for (int j = 0; j < 8; ++j) {
        unsigned short hb = f2bf(f[j]);
        h[j] = (short)hb;
        l[j] = (short)f2bf(f[j] - bf2f(hb));
    }
    const size_t o = ((size_t)chunk * 1024 + p) * 8;
    *reinterpret_cast<v8s*>(cbh + o) = h;
    *reinterpret_cast<v8s*>(cbl + o) = l;
}

// ---------------- kernel 2: MFMA argmin + fused gather/loss ----------------
// Round-1 schedule, widened to 512 threads / BM=128 / 1 staging block per CU:
//   phase A: WAITVM(2) [s.h landed] ; s_barrier ; issue (s+1).h ; 8 ds_read + 32 MFMA
//   phase B: WAITVM(2) [s.l landed] ; s_barrier ; issue (s+1).l ; 8 ds_read + 16 MFMA
// Per-wave VMEM order: ... s.h(2), s.l(2), (s+1).h(2), (s+1).l(2) ... so at each
// phase entry the needed 2 loads are the oldest of 4 outstanding; WAITVM(2) never
// drains the queue. sched_barrier(0) pins compiler motion at each sync edge so
// no ds_read can slip between WAITVM and s_barrier (see SCHEDFENCE comment).
__global__ __launch_bounds__(512, 2) void vq_argmin_mfma(
        const float* __restrict__ x, const float* __restrict__ cb,
        const unsigned short* __restrict__ cbh, const unsigned short* __restrict__ cbl,
        const float* __restrict__ c2, float* __restrict__ idx_out,
        float* __restrict__ qout, float* __restrict__ loss, float scale, int N) {
    __shared__ unsigned short lds_h[2][8192];   // 2 x 16 KB (double-buffered h-chunks)
    __shared__ unsigned short lds_l[2][8192];   // 2 x 16 KB
    __shared__ float c2s[2048];                 // 8 KB  -> 72 KB total

    const int tid  = threadIdx.x;
    const int w    = tid >> 6;      // 8 waves
    const int lane = tid & 63;
    const int col  = lane & 15;     // MFMA col / A-row selector
    const int quad = lane >> 4;     // k-octet selector
    const int mg   = w >> 1;        // 0..3 : 32-row slice of the 128-row tile
    const int ng   = w & 1;         // 0..1 : 64-code half of the 128-code group
    const int m0   = blockIdx.x * BM;
    const int n_groups = N >> 7;
    const int n_stages = n_groups * 4;

    // per-wave staging: wave w stages granules [w*128, w*128+128) of each chunk
    const unsigned short* gh0 = cbh + ((size_t)(w * 128 + lane)) * 8;
    const unsigned short* gl0 = cbl + ((size_t)(w * 128 + lane)) * 8;

    // prologue: issue stage 0 (h then l); flies during setup below
    gl_lds16(gh0,       &lds_h[0][w * 1024]);
    gl_lds16(gh0 + 512, &lds_h[0][w * 1024 + 512]);
    gl_lds16(gl0,       &lds_l[0][w * 1024]);
    gl_lds16(gl0 + 512, &lds_l[0][w * 1024 + 512]);

    // ---- c2 -> LDS ----
    {
        const int o = tid * 8;
        if (o < N) {
            const float4 a = *reinterpret_cast<const float4*>(c2 + o);
            const float4 b = *reinterpret_cast<const float4*>(c2 + o + 4);
            *reinterpret_cast<float4*>(&c2s[o])     = a;
            *reinterpret_cast<float4*>(&c2s[o + 4]) = b;
        }
    }

    // ---- A-frags: rows m0 + mg*32 + mt*16 + col, full K, hi+lo (128 VGPR) ----
    v8s xh[2][8], xl[2][8];
    #pragma unroll
    for (int mt = 0; mt < 2; ++mt) {
        const float* xr = x + (size_t)(m0 + mg * 32 + mt * 16 + col) * D;
        #pragma unroll
        for (int ks = 0; ks < 8; ++ks) {
            const int kb = ks * 32 + quad * 8;
            const float4 f0 = *reinterpret_cast<const float4*>(xr + kb);
            const float4 f1 = *reinterpret_cast<const float4*>(xr + kb + 4);
            float f[8] = {f0.x, f0.y, f0.z, f0.w, f1.x, f1.y, f1.z, f1.w};
            v8s h, l;
            #pragma unroll
            for (int j = 0; j < 8; ++j) {
                unsigned short hb = f2bf(f[j]);
                h[j] = (short)hb;
                l[j] = (short)f2bf(f[j] - bf2f(hb));
            }
            xh[mt][ks] = h; xl[mt][ks] = l;
        }
    }

    float runmin[2][4];
    int   runidx[2][4];
    #pragma unroll
    for (int mt = 0; mt < 2; ++mt)
        #pragma unroll
        for (int r = 0; r < 4; ++r) { runmin[mt][r] = 3.4e38f; runidx[mt][r] = 0; }

    v4f acc[4][2];
    #pragma unroll
    for (int nt = 0; nt < 4; ++nt)
        #pragma unroll
        for (int mt = 0; mt < 2; ++mt) acc[nt][mt] = 0.0f;

    __syncthreads();   // publish c2s; full drain (prologue-once) -> stage 0 landed

    for (int g = 0; g < n_groups; ++g) {
        #pragma unroll
        for (int cc = 0; cc < 4; ++cc) {           // compile-time chunk index
            const int par   = cc & 1;              // static buffer parity
            const int stage = g * 4 + cc;
            const bool more = (stage + 1 < n_stages);

            // ================= phase A: hi-half =================
            WAITVM(2);                              // s.h landed (s.l may fly)
            SCHEDFENCE();
            __builtin_amdgcn_s_barrier();           // all waves' s.h published
            SCHEDFENCE();
            if (more) {
                const unsigned short* gh = gh0 + (size_t)(stage + 1) * 8192;
                unsigned short* lh = &lds_h[par ^ 1][w * 1024];
                gl_lds16(gh,       lh);
                gl_lds16(gh + 512, lh + 512);
            }
            __builtin_amdgcn_s_setprio(1);
            #pragma unroll
            for (int ksk = 0; ksk < 2; ++ksk) {
                const int ks  = cc * 2 + ksk;       // static 0..7
                const int seg = ksk * 4 + quad;     // 0..7
                #pragma unroll
                for (int nt = 0; nt < 4; ++nt) {
                    const int p = seg * BN + ((ng * 64 + nt * 16 + col) ^ seg);
                    const v8s ch = *reinterpret_cast<const v8s*>(&lds_h[par][p * 8]);
                    #pragma unroll
                    for (int mt = 0; mt < 2; ++mt) {
                        acc[nt][mt] = MFMA16(xh[mt][ks], ch, acc[nt][mt], 0, 0, 0);
                        acc[nt][mt] = MFMA16(xl[mt][ks], ch, acc[nt][mt], 0, 0, 0);
                    }
                }
            }
            __builtin_amdgcn_s_setprio(0);

            // ================= phase B: lo-half =================
            if (more) { WAITVM(2); }                // s.l landed ((s+1).h may fly)
            else      { WAITVM(0); }                // last stage: drain
            SCHEDFENCE();
            __builtin_amdgcn_s_barrier();
            SCHEDFENCE();
            if (more) {
                const unsigned short* gl = gl0 + (size_t)(stage + 1) * 8192;
                unsigned short* ll = &lds_l[par ^ 1][w * 1024];
                gl_lds16(gl,       ll);
                gl_lds16(gl + 512, ll + 512);
            }
            __builtin_amdgcn_s_setprio(1);
            #pragma unroll
            for (int ksk = 0; ksk < 2; ++ksk) {
                const int ks  = cc * 2 + ksk;
                const int seg = ksk * 4 + quad;
                #pragma unroll
                for (int nt = 0; nt < 4; ++nt) {
                    const int p = seg * BN + ((ng * 64 + nt * 16 + col) ^ seg);
                    const v8s cl = *reinterpret_cast<const v8s*>(&lds_l[par][p * 8]);
                    #pragma unroll
                    for (int mt = 0; mt < 2; ++mt)
                        acc[nt][mt] = MFMA16(xh[mt][ks], cl, acc[nt][mt], 0, 0, 0);
                }
            }
            __builtin_amdgcn_s_setprio(0);
        }

        // finalize this n-group (registers + read-only c2s — no barrier needed)
        #pragma unroll
        for (int nt = 0; nt < 4; ++nt) {
            const int n = g * BN + ng * 64 + nt * 16 + col;
            const float c2n = c2s[n];
            #pragma unroll
            for (int mt = 0; mt < 2; ++mt) {
                #pragma unroll
                for (int r = 0; r < 4; ++r) {
                    const float s = c2n - 2.0f * acc[nt][mt][r];
                    if (s < runmin[mt][r]) { runmin[mt][r] = s; runidx[mt][r] = n; }
                }
                acc[nt][mt] = 0.0f;
            }
        }
    }

    // ---- merge: row = mg*32 + mt*16 + quad*4 + r ; slot = (ng*16+col) ^ (row&31) ----
    __syncthreads();
    float* red_v = reinterpret_cast<float*>(&lds_h[0][0]);   // [128][32] f32, 16 KB
    int*   red_i = reinterpret_cast<int*>(&lds_l[0][0]);     // [128][32] i32, 16 KB
    #pragma unroll
    for (int mt = 0; mt < 2; ++mt)
        #pragma unroll
        for (int r = 0; r < 4; ++r) {
            const int row  = mg * 32 + mt * 16 + quad * 4 + r;
            const int slot = (ng * 16 + col) ^ (row & 31);
            red_v[row * 32 + slot] = runmin[mt][r];
            red_i[row * 32 + slot] = runidx[mt][r];
        }
    __syncthreads();
    float best = 3.4e38f;
    int   bidx = 0;
    if (tid < 128) {
        #pragma unroll 4
        for (int t = 0; t < 32; ++t) {
            const int  sl = t ^ (tid & 31);
            const float v = red_v[tid * 32 + sl];
            const int  id = red_i[tid * 32 + sl];
            if (v < best || (v == best && id < bidx)) { best = v; bidx = id; }
        }
        idx_out[m0 + tid] = (float)bidx;
    }
    __syncthreads();
    int* idx_sh = reinterpret_cast<int*>(&lds_h[1][0]);
    if (tid < 128) idx_sh[tid] = bidx;
    __syncthreads();

    // ---- fused gather + loss over this block's 128 rows (x tile is L2-hot) ----
    const float* xg2 = x + (size_t)m0 * D;
    float s = 0.0f;
    #pragma unroll
    for (int i = 0; i < 16; ++i) {
        const int gix = i * 512 + tid;      // float4-granule, 8192 total
        const int row = gix >> 6;
        const int k4  = (gix & 63) * 4;
        const int idx = idx_sh[row];
        const float4 c  = *reinterpret_cast<const float4*>(cb  + (size_t)idx * D + k4);
        const float4 xv = *reinterpret_cast<const float4*>(xg2 + (size_t)row * D + k4);
        *reinterpret_cast<float4*>(qout + (size_t)(m0 + row) * D + k4) = c;
        const float dx = c.x - xv.x, dy = c.y - xv.y, dz = c.z - xv.z, dw = c.w - xv.w;
        s += dx * dx + dy * dy + dz * dz + dw * dw;
    }
    #pragma unroll
    for (int off = 32; off > 0; off >>= 1) s += __shfl_down(s, off, 64);
    float* wsum = reinterpret_cast<float*>(&lds_l[1][0]);
    if ((tid & 63) == 0) wsum[tid >> 6] = s;
    __syncthreads();
    if (tid == 0) {
        float t = 0.0f;
        #pragma unroll
        for (int i = 0; i < 8; ++i) t += wsum[i];
        atomicAdd(loss, t * scale);
    }
}

extern "C" void kernel_launch(void* const* d_in, const int* in_sizes, int n_in,
                              void* d_out, int out_size, void* d_ws, size_t ws_size,
                              hipStream_t stream) {
    const float* x  = (const float*)d_in[0];
    const float* cb = (const float*)d_in[1];
    const int M = in_sizes[0] / D;   // 32768
    const int N = in_sizes[1] / D;   // 2048

    float* qout    = (float*)d_out;
    float* idx_out = qout + (size_t)M * D;
    float* loss    = idx_out + M;

    // ws layout (bytes): c2 [0,8K) | cbh_sw [8K, +1M) | cbl_sw [+1M)
    char* wsb = (char*)d_ws;
    float*          c2  = (float*)wsb;
    unsigned short* cbh = (unsigned short*)(wsb + 8192);
    unsigned short* cbl = cbh + (size_t)N * D;

    vq_prep_c2<<<N, 64, 0, stream>>>(cb, c2, loss);
    vq_prep_sw<<<(N / BN) * 4 * 4, 256, 0, stream>>>(cb, cbh, cbl);
    const float scale = 2.0f / (float)((size_t)M * D);
    vq_argmin_mfma<<<M / BM, 512, 0, stream>>>(x, cb, cbh, cbl, c2, idx_out, qout,
                                               loss, scale, N);
}

// Round 7
// 194.498 us; speedup vs baseline: 1.1544x; 1.1501x over previous
//
#include <hip/hip_runtime.h>

#define D   256
#define BM  64      // rows per block (4 waves, 256 threads, 2 blocks/CU)
#define BN  128     // codes per group

typedef __attribute__((ext_vector_type(8))) short v8s;   // 8 bf16 = 4 VGPR
typedef __attribute__((ext_vector_type(4))) float v4f;
#define MFMA16 __builtin_amdgcn_mfma_f32_16x16x32_bf16

// counted vmcnt wait; "memory" clobber pins VMEM issue order around it.
#define WAITVM(N) asm volatile("s_waitcnt vmcnt(" #N ")" ::: "memory")
// compile-time scheduler fence (runtime-free). Raw s_barrier is NOT a compiler
// memory fence — without this, LLVM may hoist a ds_read of the freshly-staged
// buffer above the barrier, reading another wave's staging region before that
// wave's WAITVM certified its DMA landed (the r5 race).
#define SCHEDFENCE() __builtin_amdgcn_sched_barrier(0)

static __device__ inline unsigned short f2bf(float f) {          // RNE
    unsigned u = __float_as_uint(f);
    return (unsigned short)((u + 0x7fffu + ((u >> 16) & 1u)) >> 16);
}
static __device__ inline float bf2f(unsigned short s) {
    return __uint_as_float(((unsigned)s) << 16);
}

// async global->LDS, 16 B per lane. LDS dest must be wave-uniform (HW adds lane*16).
static __device__ inline void gl_lds16(const unsigned short* g, unsigned short* l) {
    __builtin_amdgcn_global_load_lds(
        (const __attribute__((address_space(1))) unsigned int*)g,
        (__attribute__((address_space(3))) unsigned int*)l, 16, 0, 0);
}

// ---------------- kernel 1a: exact c2 (+ zero the loss accumulator) ----------------
__global__ void vq_prep_c2(const float* __restrict__ cb, float* __restrict__ c2,
                           float* __restrict__ loss) {
    const int row  = blockIdx.x;
    const int lane = threadIdx.x;  // 64
    if (row == 0 && lane == 0) loss[0] = 0.0f;
    const float4 v = *reinterpret_cast<const float4*>(cb + (size_t)row * D + lane * 4);
    float s = v.x * v.x + v.y * v.y + v.z * v.z + v.w * v.w;
    #pragma unroll
    for (int off = 32; off > 0; off >>= 1) s += __shfl_down(s, off, 64);
    if (lane == 0) c2[row] = s;
}

// ---------------- kernel 1b: codebook -> bf16 hi/lo, chunk-major pre-swizzled ----------------
// Chunk (nc_i, kc_i) = 128 codes x 64 k = 1024 granules of 16 B (8 bf16).
// Granule p within chunk: seg = p>>7 (k-octet 0..7), n = (p&127) ^ seg.
// Lane-linear DMA reproduces this in LDS: MFMA read octets (col 0..7, seg const)
// hit bank-groups (col^seg)&7, all distinct -> conflict-free.
__global__ void vq_prep_sw(const float* __restrict__ cb,
                           unsigned short* __restrict__ cbh, unsigned short* __restrict__ cbl) {
    const int b     = blockIdx.x;          // 256 blocks, 4 per chunk
    const int chunk = b >> 2;
    const int nc = (chunk >> 2) * BN;
    const int kc = (chunk & 3) * 64;
    const int p   = (b & 3) * 256 + threadIdx.x;
    const int seg = p >> 7;
    const int n   = (p & 127) ^ seg;
    const float* src = cb + (size_t)(nc + n) * D + kc + seg * 8;
    const float4 f0 = *reinterpret_cast<const float4*>(src);
    const float4 f1 = *reinterpret_cast<const float4*>(src + 4);
    const float f[8] = {f0.x, f0.y, f0.z, f0.w, f1.x, f1.y, f1.z, f1.w};
    v8s h, l;
    #pragma unroll
    for (int j = 0; j < 8; ++j) {
        unsigned short hb = f2bf(f[j]);
        h[j] = (short)hb;
        l[j] = (short)f2bf(f[j] - bf2f(hb));
    }
    const size_t o = ((size_t)chunk * 1024 + p) * 8;
    *reinterpret_cast<v8s*>(cbh + o) = h;
    *reinterpret_cast<v8s*>(cbl + o) = l;
}

// ---------------- kernel 2: MFMA argmin + fused gather/loss ----------------
// One phase per chunk s (r1 geometry, merged A+B phases):
//   WAITVM(0)  : own 8 stage-s DMAs landed (issued one full chunk earlier,
//                ~2000 cyc in flight -> drain is free)
//   s_barrier  : all waves' s published in LDS; all waves done reading par^1
//   issue s+1  : 8 DMAs (h+l) into buffer par^1
//   compute    : 16 ds_read_b128 + 48 MFMA16, one setprio-wrapped cluster
// 64 barriers/block (vs 128 in the two-phase version); the compiler pipelines
// the 16 reads into the MFMA cluster with counted lgkmcnt.
__global__ __launch_bounds__(256, 2) void vq_argmin_mfma(
        const float* __restrict__ x, const float* __restrict__ cb,
        const unsigned short* __restrict__ cbh, const unsigned short* __restrict__ cbl,
        const float* __restrict__ c2, float* __restrict__ idx_out,
        float* __restrict__ qout, float* __restrict__ loss, float scale, int N) {
    __shared__ unsigned short lds_h[2][8192];   // 2 x 16 KB (double-buffered h-chunks)
    __shared__ unsigned short lds_l[2][8192];   // 2 x 16 KB
    __shared__ float c2s[2048];                 // 8 KB  -> 72 KB, 2 blocks/CU

    const int tid  = threadIdx.x;
    const int w    = tid >> 6;      // 4 waves
    const int lane = tid & 63;
    const int col  = lane & 15;     // MFMA col / A-row selector
    const int quad = lane >> 4;     // k-octet selector
    const int mg   = w >> 1;        // 0..1 : 32-row slice
    const int ng   = w & 1;         // 0..1 : 64-code half of the group
    const int m0   = blockIdx.x * BM;
    const int n_groups = N >> 7;
    const int n_stages = n_groups * 4;

    // per-wave staging: wave w stages granules [w*256, w*256+256) of each chunk
    const unsigned short* gh0 = cbh + ((size_t)(w * 256 + lane)) * 8;
    const unsigned short* gl0 = cbl + ((size_t)(w * 256 + lane)) * 8;

    // prologue: issue stage 0 (8 DMAs); they fly during setup below
    #pragma unroll
    for (int i = 0; i < 4; ++i) {
        gl_lds16(gh0 + i * 512, &lds_h[0][(w * 256 + i * 64) * 8]);
        gl_lds16(gl0 + i * 512, &lds_l[0][(w * 256 + i * 64) * 8]);
    }

    // ---- c2 -> LDS ----
    {
        const int o = tid * 8;
        if (o < N) {
            const float4 a = *reinterpret_cast<const float4*>(c2 + o);
            const float4 b = *reinterpret_cast<const float4*>(c2 + o + 4);
            *reinterpret_cast<float4*>(&c2s[o])     = a;
            *reinterpret_cast<float4*>(&c2s[o + 4]) = b;
        }
    }

    // ---- A-frags: rows m0 + mg*32 + mt*16 + col, full K, hi+lo (128 VGPR) ----
    v8s xh[2][8], xl[2][8];
    #pragma unroll
    for (int mt = 0; mt < 2; ++mt) {
        const float* xr = x + (size_t)(m0 + mg * 32 + mt * 16 + col) * D;
        #pragma unroll
        for (int ks = 0; ks < 8; ++ks) {
            const int kb = ks * 32 + quad * 8;
            const float4 f0 = *reinterpret_cast<const float4*>(xr + kb);
            const float4 f1 = *reinterpret_cast<const float4*>(xr + kb + 4);
            float f[8] = {f0.x, f0.y, f0.z, f0.w, f1.x, f1.y, f1.z, f1.w};
            v8s h, l;
            #pragma unroll
            for (int j = 0; j < 8; ++j) {
                unsigned short hb = f2bf(f[j]);
                h[j] = (short)hb;
                l[j] = (short)f2bf(f[j] - bf2f(hb));
            }
            xh[mt][ks] = h; xl[mt][ks] = l;
        }
    }

    float runmin[2][4];
    int   runidx[2][4];
    #pragma unroll
    for (int mt = 0; mt < 2; ++mt)
        #pragma unroll
        for (int r = 0; r < 4; ++r) { runmin[mt][r] = 3.4e38f; runidx[mt][r] = 0; }

    v4f acc[4][2];
    #pragma unroll
    for (int nt = 0; nt < 4; ++nt)
        #pragma unroll
        for (int mt = 0; mt < 2; ++mt) acc[nt][mt] = 0.0f;

    __syncthreads();   // publish c2s (prologue-once full drain; stage 0 landed)

    for (int g = 0; g < n_groups; ++g) {
        #pragma unroll
        for (int cc = 0; cc < 4; ++cc) {           // compile-time chunk index
            const int par   = cc & 1;              // static buffer parity
            const int stage = g * 4 + cc;
            const bool more = (stage + 1 < n_stages);

            SCHEDFENCE();
            WAITVM(0);                              // own stage-s DMAs landed
            SCHEDFENCE();
            __builtin_amdgcn_s_barrier();           // publish s; par^1 reusable
            SCHEDFENCE();
            if (more) {                             // issue s+1 into par^1
                const unsigned short* gh = gh0 + (size_t)(stage + 1) * 8192;
                const unsigned short* gl = gl0 + (size_t)(stage + 1) * 8192;
                unsigned short* lh = &lds_h[par ^ 1][0];
                unsigned short* ll = &lds_l[par ^ 1][0];
                #pragma unroll
                for (int i = 0; i < 4; ++i) {
                    gl_lds16(gh + i * 512, lh + (w * 256 + i * 64) * 8);
                    gl_lds16(gl + i * 512, ll + (w * 256 + i * 64) * 8);
                }
            }
            __builtin_amdgcn_s_setprio(1);
            #pragma unroll
            for (int ksk = 0; ksk < 2; ++ksk) {
                const int ks  = cc * 2 + ksk;       // static 0..7
                const int seg = ksk * 4 + quad;     // 0..7
                #pragma unroll
                for (int nt = 0; nt < 4; ++nt) {
                    const int p = seg * BN + ((ng * 64 + nt * 16 + col) ^ seg);
                    const v8s ch = *reinterpret_cast<const v8s*>(&lds_h[par][p * 8]);
                    const v8s cl = *reinterpret_cast<const v8s*>(&lds_l[par][p * 8]);
                    #pragma unroll
                    for (int mt = 0; mt < 2; ++mt) {
                        acc[nt][mt] = MFMA16(xh[mt][ks], ch, acc[nt][mt], 0, 0, 0);
                        acc[nt][mt] = MFMA16(xl[mt][ks], ch, acc[nt][mt], 0, 0, 0);
                        acc[nt][mt] = MFMA16(xh[mt][ks], cl, acc[nt][mt], 0, 0, 0);
                    }
                }
            }
            __builtin_amdgcn_s_setprio(0);
        }

        // finalize this n-group (registers + read-only c2s — no barrier needed)
        #pragma unroll
        for (int nt = 0; nt < 4; ++nt) {
            const int n = g * BN + ng * 64 + nt * 16 + col;
            const float c2n = c2s[n];
            #pragma unroll
            for (int mt = 0; mt < 2; ++mt) {
                #pragma unroll
                for (int r = 0; r < 4; ++r) {
                    const float s = c2n - 2.0f * acc[nt][mt][r];
                    if (s < runmin[mt][r]) { runmin[mt][r] = s; runidx[mt][r] = n; }
                }
                acc[nt][mt] = 0.0f;
            }
        }
    }

    // ---- merge: row = mg*32 + mt*16 + quad*4 + r ; slot = (ng*16+col) ^ (row&31) ----
    __syncthreads();
    float* red_v = reinterpret_cast<float*>(&lds_h[0][0]);   // [64][32] f32, 8 KB
    int*   red_i = reinterpret_cast<int*>(&lds_l[0][0]);     // [64][32] i32, 8 KB
    #pragma unroll
    for (int mt = 0; mt < 2; ++mt)
        #pragma unroll
        for (int r = 0; r < 4; ++r) {
            const int row  = mg * 32 + mt * 16 + quad * 4 + r;
            const int slot = (ng * 16 + col) ^ (row & 31);
            red_v[row * 32 + slot] = runmin[mt][r];
            red_i[row * 32 + slot] = runidx[mt][r];
        }
    __syncthreads();
    float best = 3.4e38f;
    int   bidx = 0;
    if (tid < 64) {
        #pragma unroll 4
        for (int t = 0; t < 32; ++t) {
            const int  sl = t ^ (tid & 31);
            const float v = red_v[tid * 32 + sl];
            const int  id = red_i[tid * 32 + sl];
            if (v < best || (v == best && id < bidx)) { best = v; bidx = id; }
        }
        idx_out[m0 + tid] = (float)bidx;
    }
    __syncthreads();
    int* idx_sh = reinterpret_cast<int*>(&lds_h[1][0]);
    if (tid < 64) idx_sh[tid] = bidx;
    __syncthreads();

    // ---- fused gather + loss over this block's 64 rows (x tile is L2-hot) ----
    const float* xg2 = x + (size_t)m0 * D;
    float s = 0.0f;
    #pragma unroll
    for (int i = 0; i < 16; ++i) {
        const int gix = i * 256 + tid;      // float4-granule, 4096 total
        const int row = gix >> 6;
        const int k4  = (gix & 63) * 4;
        const int idx = idx_sh[row];
        const float4 c  = *reinterpret_cast<const float4*>(cb  + (size_t)idx * D + k4);
        const float4 xv = *reinterpret_cast<const float4*>(xg2 + (size_t)row * D + k4);
        *reinterpret_cast<float4*>(qout + (size_t)(m0 + row) * D + k4) = c;
        const float dx = c.x - xv.x, dy = c.y - xv.y, dz = c.z - xv.z, dw = c.w - xv.w;
        s += dx * dx + dy * dy + dz * dz + dw * dw;
    }
    #pragma unroll
    for (int off = 32; off > 0; off >>= 1) s += __shfl_down(s, off, 64);
    float* wsum = reinterpret_cast<float*>(&lds_l[1][0]);
    if ((tid & 63) == 0) wsum[tid >> 6] = s;
    __syncthreads();
    if (tid == 0) {
        atomicAdd(loss, (wsum[0] + wsum[1] + wsum[2] + wsum[3]) * scale);
    }
}

extern "C" void kernel_launch(void* const* d_in, const int* in_sizes, int n_in,
                              void* d_out, int out_size, void* d_ws, size_t ws_size,
                              hipStream_t stream) {
    const float* x  = (const float*)d_in[0];
    const float* cb = (const float*)d_in[1];
    const int M = in_sizes[0] / D;   // 32768
    const int N = in_sizes[1] / D;   // 2048

    float* qout    = (float*)d_out;
    float* idx_out = qout + (size_t)M * D;
    float* loss    = idx_out + M;

    // ws layout (bytes): c2 [0,8K) | cbh_sw [8K, +1M) | cbl_sw [+1M)
    char* wsb = (char*)d_ws;
    float*          c2  = (float*)wsb;
    unsigned short* cbh = (unsigned short*)(wsb + 8192);
    unsigned short* cbl = cbh + (size_t)N * D;

    vq_prep_c2<<<N, 64, 0, stream>>>(cb, c2, loss);
    vq_prep_sw<<<(N / BN) * 4 * 4, 256, 0, stream>>>(cb, cbh, cbl);
    const float scale = 2.0f / (float)((size_t)M * D);
    vq_argmin_mfma<<<M / BM, 256, 0, stream>>>(x, cb, cbh, cbl, c2, idx_out, qout,
                                               loss, scale, N);
}